// Round 5
// baseline (415.247 us; speedup 1.0000x reference)
//
#include <hip/hip_runtime.h>
#include <stdint.h>

#define Q_MAX_F 127.0f
#define EPS_F 1e-7f

typedef int   v4i  __attribute__((ext_vector_type(4)));
typedef int   v16i __attribute__((ext_vector_type(16)));
typedef float v4f  __attribute__((ext_vector_type(4)));

// ---------------------------------------------------------------------------
// Kernel 1 (fused prep): blocks [0, QB): per-row dynamic quant of x;
// blocks [QB, QB+PB): weight int32 -> int8 pack (grid-stride).
// Quant: 256 threads/row, thread t owns 16 CONSECUTIVE elems -> one v4i store.
// ---------------------------------------------------------------------------
__global__ __launch_bounds__(256) void prep_kernel(
    const float* __restrict__ x, int8_t* __restrict__ xq,
    float* __restrict__ xscale,
    const int* __restrict__ w, int8_t* __restrict__ wq,
    int M, int K, long n4, int QB) {
  const int t = threadIdx.x;
  if ((int)blockIdx.x < QB) {
    __shared__ float sm[4];
    for (int row = blockIdx.x; row < M; row += QB) {
      const float* xr = x + (size_t)row * K + t * 16;
      float v[16];
      float m = 0.f;
#pragma unroll
      for (int c = 0; c < 4; ++c) {
        v4f f = *(const v4f*)(xr + c * 4);
#pragma unroll
        for (int j = 0; j < 4; ++j) {
          v[c * 4 + j] = f[j];
          m = fmaxf(m, fabsf(f[j]));
        }
      }
#pragma unroll
      for (int off = 32; off; off >>= 1) m = fmaxf(m, __shfl_xor(m, off));
      if ((t & 63) == 0) sm[t >> 6] = m;
      __syncthreads();
      m = fmaxf(fmaxf(sm[0], sm[1]), fmaxf(sm[2], sm[3]));
      __syncthreads();  // protect sm[] reuse on next row iteration
      const float s = fmaxf(m, EPS_F) / Q_MAX_F;
      const float inv = 1.0f / s;
      if (t == 0) xscale[row] = s;
      v4i pk;
#pragma unroll
      for (int c = 0; c < 4; ++c) {
        int pw = 0;
#pragma unroll
        for (int j = 0; j < 4; ++j) {
          float q = rintf(v[c * 4 + j] * inv);  // RNE; matches jnp.round
          q = fminf(fmaxf(q, -127.f), 127.f);
          pw |= ((int)q & 0xff) << (8 * j);
        }
        pk[c] = pw;
      }
      *(v4i*)(xq + (size_t)row * K + t * 16) = pk;
    }
  } else {
    const long stride = (long)(gridDim.x - QB) * 256;
    for (long i = (long)((int)blockIdx.x - QB) * 256 + t; i < n4; i += stride) {
      v4i a = ((const v4i*)w)[i];
      ((int*)wq)[i] = (a[0] & 0xff) | ((a[1] & 0xff) << 8) |
                      ((a[2] & 0xff) << 16) | ((a[3] & 0xff) << 24);
    }
  }
}

// ---------------------------------------------------------------------------
// Kernel 2: int8 GEMM via mfma_i32_32x32x32_i8.
// 256x256 tile, 8 waves (2Mx4N), wave tile 128x64 = 4x2 frags of 32x32.
// BK=64 bytes (2 mfma k-steps). 4-slot LDS rotation (128 KB), stage kt+3,
// ONE barrier + counted vmcnt(8) per K-tile (T3+T4), setprio on MFMA (T5).
// Chunk swizzle c ^= (row>>1)&3 on both gload-source and ds_read (rule 21).
// Fused epilogue: out = acc * xscale[m]*wscale[n] + bias[n].
// ---------------------------------------------------------------------------
#define BM 256
#define BN 256

__global__ __launch_bounds__(512, 2) void w8a8_gemm_kernel(
    const int8_t* __restrict__ xq, const int8_t* __restrict__ wq,
    const float* __restrict__ xscale, const float* __restrict__ wscale,
    const float* __restrict__ bias, float* __restrict__ out,
    int M, int N, int K) {
  extern __shared__ char lds[];  // 4 slots x (A 16KB | B 16KB) = 128 KB

  const int t = threadIdx.x;
  const int lane = t & 63;
  const int wid = t >> 6;     // 0..7
  const int wr = wid >> 2;    // 0..1 -> rows [wr*128, +128)
  const int wc = wid & 3;     // 0..3 -> cols [wc*64, +64)

  const int nwg = gridDim.x;
  int bid = blockIdx.x;
  int wg = ((nwg & 7) == 0) ? ((bid & 7) * (nwg >> 3) + (bid >> 3)) : bid;

  const int nbn = N / BN;
  const int bm = (wg / nbn) * BM;
  const int bn = (wg % nbn) * BN;

  const char* gA = (const char*)xq + (size_t)bm * K;
  const char* gB = (const char*)wq + (size_t)bn * K;

  v16i acc[4][2] = {};

  // Stage part p (0=A, 1=B) of K-tile kt: 256 rows x 64B = 16KB,
  // 2 global_load_lds (1KB each) per wave. LDS dest linear, source
  // inverse-swizzled: chunk cs = (lane&3) ^ ((row>>1)&3).
  auto stage_part = [&](int kt, int p) {
    const char* gsrc = p ? gB : gA;
    char* dstbase = lds + (size_t)(kt & 3) * 32768 + p * 16384;
#pragma unroll
    for (int i = 0; i < 2; ++i) {
      const int lin = i * 8192 + wid * 1024 + lane * 16;
      const int row = lin >> 6;                      // 0..255
      const int cs = (lane & 3) ^ ((row >> 1) & 3);  // inverse swizzle
      const char* src = gsrc + (size_t)row * K + kt * 64 + cs * 16;
      __builtin_amdgcn_global_load_lds(
          (const __attribute__((address_space(1))) void*)src,
          (__attribute__((address_space(3))) void*)(dstbase + i * 8192 + wid * 1024),
          16, 0, 0);
    }
  };

  const int NT = K / 64;     // 64 K-tiles
  const int cl = lane & 31;  // row within 32-row fragment
  const int ch = lane >> 5;  // k-half within a 32B k-step

  // Prologue: stage kt 0,1,2; publish kt0 (own 4 loads of kt0 -> vmcnt(8)).
  for (int kt = 0; kt < 3; ++kt) { stage_part(kt, 0); stage_part(kt, 1); }
  asm volatile("s_waitcnt vmcnt(8)" ::: "memory");
  asm volatile("s_barrier" ::: "memory");

  for (int kt = 0; kt < NT; ++kt) {
    const char* bufA = lds + (size_t)(kt & 3) * 32768;
    const char* bufB = bufA + 16384;

    // Issue next-next-next tile's staging first (deep in-flight, T14 spirit).
    if (kt + 3 < NT) { stage_part(kt + 3, 0); stage_part(kt + 3, 1); }

    // ds_read all fragments for this K-tile (A: 8, B: 4 x b128).
    // A operand (32x32x32): lane holds row=lane&31, k-bytes (lane>>5)*16+ks*32.
    v4i a[2][4], b[2][2];
#pragma unroll
    for (int ks = 0; ks < 2; ++ks) {
#pragma unroll
      for (int fi = 0; fi < 4; ++fi) {
        const int r = wr * 128 + fi * 32 + cl;
        const int c = (ch + 2 * ks) ^ ((r >> 1) & 3);
        a[ks][fi] = *(const v4i*)(bufA + r * 64 + (c << 4));
      }
#pragma unroll
      for (int fj = 0; fj < 2; ++fj) {
        const int r = wc * 64 + fj * 32 + cl;
        const int c = (ch + 2 * ks) ^ ((r >> 1) & 3);
        b[ks][fj] = *(const v4i*)(bufB + r * 64 + (c << 4));
      }
    }

    __builtin_amdgcn_s_setprio(1);
#pragma unroll
    for (int ks = 0; ks < 2; ++ks)
#pragma unroll
      for (int fi = 0; fi < 4; ++fi)
#pragma unroll
        for (int fj = 0; fj < 2; ++fj)
          acc[fi][fj] = __builtin_amdgcn_mfma_i32_32x32x32_i8(
              a[ks][fi], b[ks][fj], acc[fi][fj], 0, 0, 0);
    __builtin_amdgcn_s_setprio(0);

    // Wait own kt+1 loads BEFORE the barrier; barrier publishes to all.
    // Outstanding: kt+1(4) + kt+2(4) + kt+3(4) -> vmcnt(8) in steady state.
    if (kt <= NT - 4)      asm volatile("s_waitcnt vmcnt(8)" ::: "memory");
    else if (kt == NT - 3) asm volatile("s_waitcnt vmcnt(4)" ::: "memory");
    else if (kt == NT - 2) asm volatile("s_waitcnt vmcnt(0)" ::: "memory");
    asm volatile("s_barrier" ::: "memory");
  }

  // Epilogue. 32x32 C/D: col = lane&31, row = (reg&3) + 8*(reg>>2) + 4*(lane>>5).
  const int hl = lane >> 5;
  const float wsc0 = wscale[bn + wc * 64 + cl];
  const float wsc1 = wscale[bn + wc * 64 + 32 + cl];
  const float bs0 = bias[bn + wc * 64 + cl];
  const float bs1 = bias[bn + wc * 64 + 32 + cl];
#pragma unroll
  for (int fi = 0; fi < 4; ++fi) {
#pragma unroll
    for (int r = 0; r < 16; ++r) {
      const int grow = bm + wr * 128 + fi * 32 + (r & 3) + 8 * (r >> 2) + 4 * hl;
      const float xs = xscale[grow];
      float* orow = out + (size_t)grow * N + bn + wc * 64 + cl;
      orow[0]  = (float)acc[fi][0][r] * (xs * wsc0) + bs0;
      orow[32] = (float)acc[fi][1][r] * (xs * wsc1) + bs1;
    }
  }
}

// ---------------------------------------------------------------------------
extern "C" void kernel_launch(void* const* d_in, const int* in_sizes, int n_in,
                              void* d_out, int out_size, void* d_ws, size_t ws_size,
                              hipStream_t stream) {
  const float* x = (const float*)d_in[0];
  const int* w = (const int*)d_in[1];
  const float* wscale = (const float*)d_in[2];
  const float* bias = (const float*)d_in[3];
  float* out = (float*)d_out;

  const int N = in_sizes[2];                  // 4096
  const long wk = (long)in_sizes[1];          // N*K
  const int K = (int)(wk / N);                // 4096
  const int M = (int)((long)in_sizes[0] / K); // 8192

  int8_t* xq = (int8_t*)d_ws;                       // M*K
  int8_t* wq = xq + (size_t)M * K;                  // N*K
  float* xscale = (float*)(wq + (size_t)N * K);     // M floats

  const long n4 = (long)N * K / 4;
  const int QB = 2048, PB = 2048;
  prep_kernel<<<QB + PB, 256, 0, stream>>>(x, xq, xscale, w, wq, M, K, n4, QB);

  const int nwg = (M / BM) * (N / BN);  // 32*16 = 512
  w8a8_gemm_kernel<<<nwg, 512, 131072, stream>>>(xq, wq, xscale, wscale, bias,
                                                 out, M, N, K);
}